// Round 21
// baseline (252.149 us; speedup 1.0000x reference)
//
#include <hip/hip_runtime.h>
#include <hip/hip_bf16.h>

#define DEV_INLINE __device__ __forceinline__

namespace {

constexpr int T = 3;
constexpr int NN = 20000;   // nodes
constexpr int NE = 100000;  // edges per time step
constexpr int D = 128;
constexpr int D2 = 256;
constexpr int NROW = T * NN;                  // 60000
constexpr size_t OUTSZ = (size_t)T * NN * D;  // elements per output tensor
constexpr int NTILE = T * (NN / 16);          // 3750 ffn row-tiles

typedef __attribute__((ext_vector_type(8))) short bf16x8;
typedef __attribute__((ext_vector_type(4))) float f32x4;
typedef __attribute__((ext_vector_type(2))) _Float16 h2;
typedef __hip_bfloat16 bf16;

DEV_INLINE unsigned short f2bf(float f) {
  __hip_bfloat16 t = __float2bfloat16(f);
  return *(unsigned short*)&t;
}
DEV_INLINE float bf2f(unsigned short u) { return __uint_as_float((unsigned)u << 16); }

// tanh-form GeLU (max |diff| vs exact-erf ~3e-3; threshold headroom 4x)
DEV_INLINE float gelu_fast(float y) {
  float y3 = y * y * y;
  return y / (1.f + __expf(-1.5957691216f * (y + 0.044715f * y3)));
}

// ---------------- edge-index dtype probe (int32 vs int64) ----------------
__global__ void k_detect(const unsigned int* __restrict__ ei32, int* __restrict__ flag) {
  int nz = 0;
  for (int i = threadIdx.x; i < 4096; i += 256)
    nz |= (ei32[2 * i + 1] != 0u);
  if (__any(nz) && (threadIdx.x & 63) == 0) atomicOr(&flag[0], 1);  // 1 => int32
}

DEV_INLINE int loadIdx(const void* ei, int is32, long long idx) {
  return is32 ? ((const int*)ei)[idx] : (int)((const long long*)ei)[idx];
}

// ---------------- CSR count + weight precast (independent work, one launch) ----------------
__global__ void k_count_precast(
    const void* __restrict__ ei, const int* __restrict__ flag, int* __restrict__ counts,
    const float* __restrict__ Wq, const float* __restrict__ Wk,
    const float* __restrict__ Wv, const float* __restrict__ W1,
    const float* __restrict__ W2, bf16* __restrict__ WqkvT, bf16* __restrict__ W1L,
    bf16* __restrict__ W2L) {
  int i = blockIdx.x * blockDim.x + threadIdx.x;
  int stride = gridDim.x * blockDim.x;
  if (i < T * NE) {
    int is32 = flag[0];
    int t = i / NE, e = i - t * NE;
    int tgt = loadIdx(ei, is32, (long long)(t * 2 + 1) * NE + e);
    atomicAdd(&counts[t * NN + tgt], 1);
  }
  for (int j = i; j < 384 * 128; j += stride) {
    int c = j >> 7, k = j & 127;
    float v = c < 128 ? Wq[k * D + c]
                      : (c < 256 ? Wk[k * D + (c - 128)] : Wv[k * D + (c - 256)]);
    WqkvT[c * 128 + k] = __float2bfloat16(v);
  }
  for (int idx = i; idx < 4 * 256 * 32; idx += stride) {
    int j = idx & 31, c = (idx >> 5) & 255, kk = idx >> 13;
    W1L[idx] = __float2bfloat16(W1[(kk * 32 + j) * D2 + c]);
  }
  for (int idx = i; idx < 8 * 128 * 32; idx += stride) {
    int j = idx & 31, c = (idx >> 5) & 127, kk = idx >> 12;
    W2L[idx] = __float2bfloat16(W2[(kk * 32 + j) * D + c]);
  }
}

__global__ void k_scan(const int* __restrict__ counts, int* __restrict__ offsets,
                       int* __restrict__ cursor) {
  int t = blockIdx.x;
  const int* c = counts + t * NN;
  int* o = offsets + t * (NN + 1);
  int* cur = cursor + t * NN;
  __shared__ int part[256];
  int tid = threadIdx.x;
  constexpr int CH = (NN + 255) / 256;
  int b = tid * CH;
  int e = min(b + CH, NN);
  int s = 0;
  for (int i = b; i < e; i++) s += c[i];
  part[tid] = s;
  __syncthreads();
  for (int d = 1; d < 256; d <<= 1) {
    int v = (tid >= d) ? part[tid - d] : 0;
    __syncthreads();
    part[tid] += v;
    __syncthreads();
  }
  int run = part[tid] - s;  // exclusive prefix
  for (int i = b; i < e; i++) { o[i] = run; cur[i] = run; run += c[i]; }
  if (tid == 255) o[NN] = part[255];
}

// ---------------- QKV via MFMA + scatter ride-along ----------------
__global__ __launch_bounds__(256) void k_qkv_mfma(
    const float* __restrict__ x, const bf16* __restrict__ WqkvT,
    const float* __restrict__ bq, const float* __restrict__ bk,
    const float* __restrict__ bv, _Float16* __restrict__ Qh, uint2* __restrict__ KV,
    const void* __restrict__ ei, const int* __restrict__ flag,
    int* __restrict__ cursor, int* __restrict__ elist) {
  __shared__ char As[64 * 256];  // 64 rows x 128 bf16, XOR-swizzled
  __shared__ char Bs[384 * 80];  // 384 cols x 32 k (pad to 40 bf16/row)
  int row0 = blockIdx.x * 64;
  int tid = threadIdx.x;
  // scatter ride-along: atomics issue early, drain under the MFMA work below
  {
    int gid = blockIdx.x * 256 + tid;
    int gstride = gridDim.x * 256;
    int is32 = flag[0];
    for (int i2 = gid; i2 < T * NE; i2 += gstride) {
      int t = i2 / NE, e2 = i2 - t * NE;
      int src = loadIdx(ei, is32, (long long)(t * 2 + 0) * NE + e2);
      int tgt = loadIdx(ei, is32, (long long)(t * 2 + 1) * NE + e2);
      int pos = atomicAdd(&cursor[t * NN + tgt], 1);
      elist[t * NE + pos] = src;
    }
  }
  for (int i = tid; i < 64 * 16; i += 256) {
    int rr = i >> 4, kb = i & 15;
    int grow = row0 + rr;
    uint4 v = make_uint4(0, 0, 0, 0);
    if (grow < NROW) {
      float4 lo = *(const float4*)&x[(size_t)grow * D + kb * 8];
      float4 hi = *(const float4*)&x[(size_t)grow * D + kb * 8 + 4];
      v.x = ((unsigned)f2bf(lo.y) << 16) | f2bf(lo.x);
      v.y = ((unsigned)f2bf(lo.w) << 16) | f2bf(lo.z);
      v.z = ((unsigned)f2bf(hi.y) << 16) | f2bf(hi.x);
      v.w = ((unsigned)f2bf(hi.w) << 16) | f2bf(hi.z);
    }
    *(uint4*)(As + rr * 256 + ((kb * 16) ^ ((rr & 7) << 4))) = v;
  }
  int wid = tid >> 6, lane = tid & 63;
  int lr = lane & 15, lg = lane >> 4;
  f32x4 acc[24];
#pragma unroll
  for (int i = 0; i < 24; i++) acc[i] = (f32x4){0.f, 0.f, 0.f, 0.f};
  for (int kk = 0; kk < 4; kk++) {
    __syncthreads();
    for (int i = tid; i < 384 * 4; i += 256) {
      int c = i >> 2, ko = (i & 3) * 8;
      *(uint4*)(Bs + c * 80 + ko * 2) =
          *(const uint4*)&WqkvT[(size_t)c * 128 + kk * 32 + ko];
    }
    __syncthreads();
    int ar = wid * 16 + lr;
    bf16x8 a = *(bf16x8*)(As + ar * 256 + ((kk * 64 + lg * 16) ^ ((ar & 7) << 4)));
#pragma unroll
    for (int nt = 0; nt < 24; nt++) {
      bf16x8 b = *(bf16x8*)(Bs + (nt * 16 + lr) * 80 + lg * 16);
      acc[nt] = __builtin_amdgcn_mfma_f32_16x16x32_bf16(a, b, acc[nt], 0, 0, 0);
    }
  }
  // Q: f16, prescaled by 1/sqrt(dk)
#pragma unroll
  for (int nt = 0; nt < 8; nt++) {
    int c = nt * 16 + lr;
    float bb = bq[c];
#pragma unroll
    for (int j = 0; j < 4; j++) {
      int orow = row0 + wid * 16 + lg * 4 + j;
      if (orow < NROW)
        Qh[(size_t)orow * D + c] = (_Float16)((acc[nt][j] + bb) * 0.25f);
    }
  }
  // K/V interleaved: KV[row][c>>1] = (k_c|k_c+1, v_c|v_c+1), written by even lr
#pragma unroll
  for (int nt = 0; nt < 8; nt++) {
    int c = nt * 16 + lr;
    float bbk = bk[c], bbv = bv[c];
#pragma unroll
    for (int j = 0; j < 4; j++) {
      int orow = row0 + wid * 16 + lg * 4 + j;
      unsigned ku =
          (unsigned)__builtin_bit_cast(unsigned short, (_Float16)(acc[nt + 8][j] + bbk));
      unsigned vu =
          (unsigned)__builtin_bit_cast(unsigned short, (_Float16)(acc[nt + 16][j] + bbv));
      unsigned kn = __shfl_xor(ku, 1, 64);
      unsigned vn = __shfl_xor(vu, 1, 64);
      if ((lr & 1) == 0 && orow < NROW)
        KV[(size_t)orow * 64 + (c >> 1)] = make_uint2((kn << 16) | ku, (vn << 16) | vu);
    }
  }
}

// ---------------- fused attention: half-wave edge pairing, x4 unrolled ----------------
DEV_INLINE float waveReduceSum(float v) {
#pragma unroll
  for (int m = 1; m < 64; m <<= 1) v += __shfl_xor(v, m, 64);
  return v;
}

template <int TS, bool TAIL>
DEV_INLINE void procPair(uint4 kv, const h2* q01, const h2* q23, float* dr, float* ds,
                         float (*ar)[4], float (*as)[4], float valid) {
  h2 k01 = __builtin_bit_cast(h2, kv.x);
  h2 v01 = __builtin_bit_cast(h2, kv.y);
  h2 k23 = __builtin_bit_cast(h2, kv.z);
  h2 v23 = __builtin_bit_cast(h2, kv.w);
  float v0 = (float)v01[0], v1 = (float)v01[1];
  float v2 = (float)v23[0], v3 = (float)v23[1];
#pragma unroll
  for (int tt = TS; tt < 3; tt++) {
    float a = __builtin_amdgcn_fdot2(q23[tt], k23, 0.f, false);
    a = __builtin_amdgcn_fdot2(q01[tt], k01, a, false);
    a += __shfl_xor(a, 1, 64);
    a += __shfl_xor(a, 2, 64);  // head dot complete within 4-lane group
    float e = __expf(a), f = __expf(-a);
    if (TAIL) { e *= valid; f *= valid; }
    dr[tt] += e; ds[tt] += f;
    ar[tt][0] += e * v0; ar[tt][1] += e * v1;
    ar[tt][2] += e * v2; ar[tt][3] += e * v3;
    as[tt][0] += f * v0; as[tt][1] += f * v1;
    as[tt][2] += f * v2; as[tt][3] += f * v3;
  }
}

__global__ __launch_bounds__(256) void k_attn(
    const _Float16* __restrict__ Qh, const uint2* __restrict__ KV,
    const float* __restrict__ x, const int* __restrict__ offsets,
    const int* __restrict__ elist, const float* __restrict__ lng,
    const float* __restrict__ lnb, bf16* __restrict__ hB, bf16* __restrict__ rb) {
  int n = blockIdx.x * 4 + (threadIdx.x >> 6);
  int l = threadIdx.x & 63;
  int sl = l & 31, half = l >> 5;
  h2 q01[3], q23[3];
#pragma unroll
  for (int tt = 0; tt < 3; tt++) {
    uint2 qu = *(const uint2*)&Qh[((size_t)tt * NN + n) * D + 4 * sl];
    q01[tt] = __builtin_bit_cast(h2, qu.x);
    q23[tt] = __builtin_bit_cast(h2, qu.y);
  }
  float dr[3] = {0.f, 0.f, 0.f}, ds[3] = {0.f, 0.f, 0.f};
  float ar[3][4] = {{0.f}}, as[3][4] = {{0.f}};
#define TSEC(TT)                                                              \
  {                                                                           \
    const int* off = offsets + TT * (NN + 1);                                 \
    int b = off[n], e = off[n + 1];                                           \
    const int* el = elist + TT * NE;                                          \
    const uint2* KVt = KV + (size_t)TT * NN * 64;                             \
    int i = b;                                                                \
    for (; i + 8 <= e; i += 8) {                                              \
      int s0 = el[i + half];                                                  \
      int s1 = el[i + 2 + half];                                              \
      int s2 = el[i + 4 + half];                                              \
      int s3 = el[i + 6 + half];                                              \
      uint4 kv0 = *(const uint4*)&KVt[(size_t)s0 * 64 + 2 * sl];              \
      uint4 kv1 = *(const uint4*)&KVt[(size_t)s1 * 64 + 2 * sl];              \
      uint4 kv2 = *(const uint4*)&KVt[(size_t)s2 * 64 + 2 * sl];              \
      uint4 kv3 = *(const uint4*)&KVt[(size_t)s3 * 64 + 2 * sl];              \
      procPair<TT, false>(kv0, q01, q23, dr, ds, ar, as, 1.f);                \
      procPair<TT, false>(kv1, q01, q23, dr, ds, ar, as, 1.f);                \
      procPair<TT, false>(kv2, q01, q23, dr, ds, ar, as, 1.f);                \
      procPair<TT, false>(kv3, q01, q23, dr, ds, ar, as, 1.f);                \
    }                                                                         \
    for (; i + 2 <= e; i += 2) {                                              \
      int s = el[i + half];                                                   \
      uint4 kv = *(const uint4*)&KVt[(size_t)s * 64 + 2 * sl];                \
      procPair<TT, false>(kv, q01, q23, dr, ds, ar, as, 1.f);                 \
    }                                                                         \
    if (i < e) {                                                              \
      int s = el[i];                                                          \
      uint4 kv = *(const uint4*)&KVt[(size_t)s * 64 + 2 * sl];                \
      procPair<TT, true>(kv, q01, q23, dr, ds, ar, as, half ? 0.f : 1.f);     \
    }                                                                         \
  }
  TSEC(0)
  TSEC(1)
  TSEC(2)
#undef TSEC
#pragma unroll
  for (int tt = 0; tt < 3; tt++) {
    dr[tt] += __shfl_xor(dr[tt], 32, 64);
    ds[tt] += __shfl_xor(ds[tt], 32, 64);
#pragma unroll
    for (int d4 = 0; d4 < 4; d4++) {
      ar[tt][d4] += __shfl_xor(ar[tt][d4], 32, 64);
      as[tt][d4] += __shfl_xor(as[tt][d4], 32, 64);
    }
  }
  float4 g4 = *(const float4*)&lng[4 * sl];
  float4 b4 = *(const float4*)&lnb[4 * sl];
#pragma unroll
  for (int tt = 0; tt < 3; tt++) {
    float4 xr = *(const float4*)&x[((size_t)tt * NN + n) * D + 4 * sl];
    float ir = 1.f / (dr[tt] + 1e-16f), is = 1.f / (ds[tt] + 1e-16f);
    float hc[4], hs[4];
    hc[0] = ar[tt][0] * ir + xr.x;
    hc[1] = ar[tt][1] * ir + xr.y;
    hc[2] = ar[tt][2] * ir + xr.z;
    hc[3] = ar[tt][3] * ir + xr.w;
#pragma unroll
    for (int j = 0; j < 4; j++) hs[j] = as[tt][j] * is;
    float mu = waveReduceSum(hc[0] + hc[1] + hc[2] + hc[3]) * (1.f / 256.f);
    float dx[4], ss = 0.f;
#pragma unroll
    for (int j = 0; j < 4; j++) { dx[j] = hc[j] - mu; ss += dx[j] * dx[j]; }
    float var = waveReduceSum(ss) * (1.f / 256.f);
    float rstd = rsqrtf(var + 1e-5f);
    float rc[4];
    rc[0] = dx[0] * rstd * g4.x + b4.x;
    rc[1] = dx[1] * rstd * g4.y + b4.y;
    rc[2] = dx[2] * rstd * g4.z + b4.z;
    rc[3] = dx[3] * rstd * g4.w + b4.w;
    float mu2 = waveReduceSum(hs[0] + hs[1] + hs[2] + hs[3]) * (1.f / 256.f);
    float ex[4], ss2 = 0.f;
#pragma unroll
    for (int j = 0; j < 4; j++) { ex[j] = hs[j] - mu2; ss2 += ex[j] * ex[j]; }
    float var2 = waveReduceSum(ss2) * (1.f / 256.f);
    float rstd2 = rsqrtf(var2 + 1e-5f);
    float rs[4];
    rs[0] = ex[0] * rstd2 * g4.x + b4.x;
    rs[1] = ex[1] * rstd2 * g4.y + b4.y;
    rs[2] = ex[2] * rstd2 * g4.z + b4.z;
    rs[3] = ex[3] * rstd2 * g4.w + b4.w;
    if (half == 0) {
      size_t base = (size_t)tt * 2 * NN;
      size_t iC = (base + n) * D + 4 * sl;
      size_t iS = (base + NN + n) * D + 4 * sl;
      *(uint2*)&hB[iC] = make_uint2(((unsigned)f2bf(hc[1]) << 16) | f2bf(hc[0]),
                                    ((unsigned)f2bf(hc[3]) << 16) | f2bf(hc[2]));
      *(uint2*)&hB[iS] = make_uint2(((unsigned)f2bf(hs[1]) << 16) | f2bf(hs[0]),
                                    ((unsigned)f2bf(hs[3]) << 16) | f2bf(hs[2]));
      *(uint2*)&rb[iC] = make_uint2(((unsigned)f2bf(rc[1]) << 16) | f2bf(rc[0]),
                                    ((unsigned)f2bf(rc[3]) << 16) | f2bf(rc[2]));
      *(uint2*)&rb[iS] = make_uint2(((unsigned)f2bf(rs[1]) << 16) | f2bf(rs[0]),
                                    ((unsigned)f2bf(rs[3]) << 16) | f2bf(rs[2]));
    }
  }
}

// ---------------- fused FFN v8: fast gelu, 4 blocks/CU, in-register combine ----------------
__global__ __launch_bounds__(512) void k_ffn_fused(
    const bf16* __restrict__ rb, const bf16* __restrict__ W1L,
    const bf16* __restrict__ W2L, const float* __restrict__ b1,
    const float* __restrict__ b2, const bf16* __restrict__ h,
    float* __restrict__ out) {
  __shared__ char As[32 * 256];  // rb tile, XOR-swizzled
  __shared__ char Gs[32 * 528];  // gelu tile bf16
  int tid = threadIdx.x;
  int wid = tid >> 6, lane = tid & 63;
  int lr = lane & 15, lg = lane >> 4;
  int wr = (wid & 1) * 16;
  int wc1 = (wid >> 1) * 64;
  int wc2 = (wid >> 1) * 32;
  int ar = wr + lr;
  bf16x8 w1f[4][4];  // [kk][nt]
#pragma unroll
  for (int kk = 0; kk < 4; kk++)
#pragma unroll
    for (int nt = 0; nt < 4; nt++)
      w1f[kk][nt] =
          *(const bf16x8*)&W1L[((size_t)kk * 256 + wc1 + nt * 16 + lr) * 32 + lg * 8];
  bf16x8 w2f[8][2];
#pragma unroll
  for (int kk = 0; kk < 8; kk++)
#pragma unroll
    for (int nt = 0; nt < 2; nt++)
      w2f[kk][nt] =
          *(const bf16x8*)&W2L[((size_t)kk * 128 + wc2 + nt * 16 + lr) * 32 + lg * 8];
  float bb1[4], bb2[2];
#pragma unroll
  for (int nt = 0; nt < 4; nt++) bb1[nt] = b1[wc1 + nt * 16 + lr];
#pragma unroll
  for (int nt = 0; nt < 2; nt++) bb2[nt] = b2[wc2 + nt * 16 + lr];
  int srr = tid >> 4, skb = tid & 15;  // As staging slot (1 uint4/thread)
  int tile = blockIdx.x;
  uint4 pref;
  {
    int t2 = tile / 1250, nb = tile - t2 * 1250;
    size_t grow = (size_t)t2 * 2 * NN + (size_t)(srr & 1) * NN + nb * 16 + (srr >> 1);
    pref = *(const uint4*)&rb[grow * D + skb * 8];
  }
  for (; tile < NTILE; tile += gridDim.x) {
    int t2 = tile / 1250, nb = tile - t2 * 1250;
    int n0 = nb * 16;
    size_t base = (size_t)t2 * 2 * NN;
    *(uint4*)(As + srr * 256 + ((skb * 16) ^ ((srr & 7) << 4))) = pref;
    float hpref[2][4];
#pragma unroll
    for (int nt = 0; nt < 2; nt++) {
      int c = wc2 + nt * 16 + lr;
#pragma unroll
      for (int j = 0; j < 4; j++) {
        int rr2 = wr + lg * 4 + j;
        hpref[nt][j] = bf2f(*(const unsigned short*)&h[
            (base + (size_t)(rr2 & 1) * NN + n0 + (rr2 >> 1)) * D + c]);
      }
    }
    int ntile = tile + gridDim.x;
    if (ntile < NTILE) {
      int t2n = ntile / 1250, nbn = ntile - t2n * 1250;
      size_t grow =
          (size_t)t2n * 2 * NN + (size_t)(srr & 1) * NN + nbn * 16 + (srr >> 1);
      pref = *(const uint4*)&rb[grow * D + skb * 8];
    }
    __syncthreads();  // As ready; also orders prev GEMM2 Gs-reads before Gs writes
    f32x4 acc1[4];
#pragma unroll
    for (int i = 0; i < 4; i++) acc1[i] = (f32x4){0.f, 0.f, 0.f, 0.f};
#pragma unroll
    for (int kk = 0; kk < 4; kk++) {
      bf16x8 a = *(bf16x8*)(As + ar * 256 + ((kk * 64 + lg * 16) ^ ((ar & 7) << 4)));
#pragma unroll
      for (int nt = 0; nt < 4; nt++)
        acc1[nt] =
            __builtin_amdgcn_mfma_f32_16x16x32_bf16(a, w1f[kk][nt], acc1[nt], 0, 0, 0);
    }
#pragma unroll
    for (int nt = 0; nt < 4; nt++) {
      int c = wc1 + nt * 16 + lr;
#pragma unroll
      for (int j = 0; j < 4; j++) {
        int r = wr + lg * 4 + j;
        float y = gelu_fast(acc1[nt][j] + bb1[nt]);
        unsigned us = f2bf(y);
        unsigned nbv = __shfl_xor(us, 1, 64);
        if ((lr & 1) == 0) *(unsigned*)(Gs + r * 528 + c * 2) = (nbv << 16) | us;
      }
    }
    __syncthreads();  // Gs ready
    f32x4 acc2[2];
#pragma unroll
    for (int i = 0; i < 2; i++) acc2[i] = (f32x4){0.f, 0.f, 0.f, 0.f};
#pragma unroll
    for (int kk = 0; kk < 8; kk++) {
      bf16x8 a = *(bf16x8*)(Gs + ar * 528 + kk * 64 + lg * 16);
#pragma unroll
      for (int nt = 0; nt < 2; nt++)
        acc2[nt] =
            __builtin_amdgcn_mfma_f32_16x16x32_bf16(a, w2f[kk][nt], acc2[nt], 0, 0, 0);
    }
    // epilogue fully in-register: j pairs (2m,2m+1) = (causal,spurious) of one node
#pragma unroll
    for (int nt = 0; nt < 2; nt++) {
      int c = wc2 + nt * 16 + lr;
      float z[4];
#pragma unroll
      for (int j = 0; j < 4; j++) z[j] = acc2[nt][j] + bb2[nt] + hpref[nt][j];
#pragma unroll
      for (int m = 0; m < 2; m++) {
        int node = n0 + ((wr + lg * 4) >> 1) + m;
        size_t oidx = ((size_t)t2 * NN + node) * D + c;
        out[OUTSZ + oidx] = z[2 * m];          // cs
        out[2 * OUTSZ + oidx] = z[2 * m + 1];  // ss
        out[oidx] = z[2 * m] + z[2 * m + 1];   // xs
      }
    }
  }
}

}  // namespace

extern "C" void kernel_launch(void* const* d_in, const int* in_sizes, int n_in,
                              void* d_out, int out_size, void* d_ws, size_t ws_size,
                              hipStream_t stream) {
  const float* x = (const float*)d_in[0];
  const void* ei = d_in[1];  // int32 or int64 — probed on device
  const float* Wq = (const float*)d_in[2];
  const float* bq = (const float*)d_in[3];
  const float* Wk = (const float*)d_in[4];
  const float* bk = (const float*)d_in[5];
  const float* Wv = (const float*)d_in[6];
  const float* bv = (const float*)d_in[7];
  const float* lng = (const float*)d_in[8];
  const float* lnb = (const float*)d_in[9];
  const float* W1 = (const float*)d_in[10];
  const float* b1 = (const float*)d_in[11];
  const float* W2 = (const float*)d_in[12];
  const float* b2 = (const float*)d_in[13];
  float* out = (float*)d_out;

  char* ws = (char*)d_ws;
  size_t off = 0;
  auto alloc = [&](size_t bytes) -> void* {
    void* p = ws + off;
    off += (bytes + 255) & ~(size_t)255;
    return p;
  };
  bf16* WqkvT = (bf16*)alloc((size_t)384 * 128 * 2);
  bf16* W1L = (bf16*)alloc((size_t)128 * 256 * 2);
  bf16* W2L = (bf16*)alloc((size_t)256 * 128 * 2);
  _Float16* Qh = (_Float16*)alloc((size_t)NROW * D * 2);
  uint2* KV = (uint2*)alloc((size_t)NROW * 64 * 8);
  bf16* hB = (bf16*)alloc((size_t)T * 2 * NN * D * 2);  // [t][side][node] bf16
  bf16* rb = (bf16*)alloc((size_t)T * 2 * NN * D * 2);
  int* counts = (int*)alloc((size_t)T * NN * 4);
  int* offsets = (int*)alloc((size_t)T * (NN + 1) * 4);
  int* cursor = (int*)alloc((size_t)T * NN * 4);
  int* elist = (int*)alloc((size_t)T * NE * 4);
  int* dflag = (int*)alloc(256);

  hipMemsetAsync(counts, 0, (size_t)T * NN * 4, stream);
  hipMemsetAsync(dflag, 0, 8, stream);
  k_detect<<<1, 256, 0, stream>>>((const unsigned int*)ei, dflag);
  int eb = (T * NE + 255) / 256;
  k_count_precast<<<eb, 256, 0, stream>>>(ei, dflag, counts, Wq, Wk, Wv, W1, W2,
                                          WqkvT, W1L, W2L);
  k_scan<<<T, 256, 0, stream>>>(counts, offsets, cursor);
  k_qkv_mfma<<<(NROW + 63) / 64, 256, 0, stream>>>(x, WqkvT, bq, bk, bv, Qh, KV, ei,
                                                   dflag, cursor, elist);
  k_attn<<<NN / 4, 256, 0, stream>>>(Qh, KV, x, offsets, elist, lng, lnb, hB, rb);
  k_ffn_fused<<<1024, 512, 0, stream>>>(rb, W1L, W2L, b1, b2, hB, out);
}

// Round 22
// 241.291 us; speedup vs baseline: 1.0450x; 1.0450x over previous
//
#include <hip/hip_runtime.h>
#include <hip/hip_bf16.h>

#define DEV_INLINE __device__ __forceinline__

namespace {

constexpr int T = 3;
constexpr int NN = 20000;   // nodes
constexpr int NE = 100000;  // edges per time step
constexpr int D = 128;
constexpr int D2 = 256;
constexpr int NROW = T * NN;                  // 60000
constexpr size_t OUTSZ = (size_t)T * NN * D;  // elements per output tensor
constexpr int NTILE = T * (NN / 16);          // 3750 ffn row-tiles

typedef __attribute__((ext_vector_type(8))) short bf16x8;
typedef __attribute__((ext_vector_type(4))) float f32x4;
typedef __attribute__((ext_vector_type(2))) _Float16 h2;
typedef __hip_bfloat16 bf16;

DEV_INLINE unsigned short f2bf(float f) {
  __hip_bfloat16 t = __float2bfloat16(f);
  return *(unsigned short*)&t;
}
DEV_INLINE float bf2f(unsigned short u) { return __uint_as_float((unsigned)u << 16); }

// tanh-form GeLU (max |diff| vs exact-erf ~3e-3; threshold headroom 4x)
DEV_INLINE float gelu_fast(float y) {
  float y3 = y * y * y;
  return y / (1.f + __expf(-1.5957691216f * (y + 0.044715f * y3)));
}

// ---------------- edge-index dtype probe (int32 vs int64) ----------------
__global__ void k_detect(const unsigned int* __restrict__ ei32, int* __restrict__ flag) {
  int nz = 0;
  for (int i = threadIdx.x; i < 4096; i += 256)
    nz |= (ei32[2 * i + 1] != 0u);
  if (__any(nz) && (threadIdx.x & 63) == 0) atomicOr(&flag[0], 1);  // 1 => int32
}

DEV_INLINE int loadIdx(const void* ei, int is32, long long idx) {
  return is32 ? ((const int*)ei)[idx] : (int)((const long long*)ei)[idx];
}

// ---------------- CSR count + weight precast (independent work, one launch) ----------------
__global__ void k_count_precast(
    const void* __restrict__ ei, const int* __restrict__ flag, int* __restrict__ counts,
    const float* __restrict__ Wq, const float* __restrict__ Wk,
    const float* __restrict__ Wv, const float* __restrict__ W1,
    const float* __restrict__ W2, bf16* __restrict__ WqkvT, bf16* __restrict__ W1L,
    bf16* __restrict__ W2L) {
  int i = blockIdx.x * blockDim.x + threadIdx.x;
  int stride = gridDim.x * blockDim.x;
  if (i < T * NE) {
    int is32 = flag[0];
    int t = i / NE, e = i - t * NE;
    int tgt = loadIdx(ei, is32, (long long)(t * 2 + 1) * NE + e);
    atomicAdd(&counts[t * NN + tgt], 1);
  }
  for (int j = i; j < 384 * 128; j += stride) {
    int c = j >> 7, k = j & 127;
    float v = c < 128 ? Wq[k * D + c]
                      : (c < 256 ? Wk[k * D + (c - 128)] : Wv[k * D + (c - 256)]);
    WqkvT[c * 128 + k] = __float2bfloat16(v);
  }
  for (int idx = i; idx < 4 * 256 * 32; idx += stride) {
    int j = idx & 31, c = (idx >> 5) & 255, kk = idx >> 13;
    W1L[idx] = __float2bfloat16(W1[(kk * 32 + j) * D2 + c]);
  }
  for (int idx = i; idx < 8 * 128 * 32; idx += stride) {
    int j = idx & 31, c = (idx >> 5) & 127, kk = idx >> 12;
    W2L[idx] = __float2bfloat16(W2[(kk * 32 + j) * D + c]);
  }
}

__global__ void k_scan(const int* __restrict__ counts, int* __restrict__ offsets,
                       int* __restrict__ cursor) {
  int t = blockIdx.x;
  const int* c = counts + t * NN;
  int* o = offsets + t * (NN + 1);
  int* cur = cursor + t * NN;
  __shared__ int part[256];
  int tid = threadIdx.x;
  constexpr int CH = (NN + 255) / 256;
  int b = tid * CH;
  int e = min(b + CH, NN);
  int s = 0;
  for (int i = b; i < e; i++) s += c[i];
  part[tid] = s;
  __syncthreads();
  for (int d = 1; d < 256; d <<= 1) {
    int v = (tid >= d) ? part[tid - d] : 0;
    __syncthreads();
    part[tid] += v;
    __syncthreads();
  }
  int run = part[tid] - s;  // exclusive prefix
  for (int i = b; i < e; i++) { o[i] = run; cur[i] = run; run += c[i]; }
  if (tid == 255) o[NN] = part[255];
}

__global__ void k_scatter(const void* __restrict__ ei, const int* __restrict__ flag,
                          int* __restrict__ cursor, int* __restrict__ elist) {
  int i = blockIdx.x * blockDim.x + threadIdx.x;
  if (i >= T * NE) return;
  int is32 = flag[0];
  int t = i / NE, e = i - t * NE;
  int src = loadIdx(ei, is32, (long long)(t * 2 + 0) * NE + e);
  int tgt = loadIdx(ei, is32, (long long)(t * 2 + 1) * NE + e);
  int pos = atomicAdd(&cursor[t * NN + tgt], 1);
  elist[t * NE + pos] = src;
}

// ---------------- QKV via MFMA -> f16 Q(prescaled) + interleaved KV ----------------
__global__ __launch_bounds__(256) void k_qkv_mfma(
    const float* __restrict__ x, const bf16* __restrict__ WqkvT,
    const float* __restrict__ bq, const float* __restrict__ bk,
    const float* __restrict__ bv,
    _Float16* __restrict__ Qh, uint2* __restrict__ KV) {
  __shared__ char As[64 * 256];  // 64 rows x 128 bf16, XOR-swizzled
  __shared__ char Bs[384 * 80];  // 384 cols x 32 k (pad to 40 bf16/row)
  int row0 = blockIdx.x * 64;
  int tid = threadIdx.x;
  for (int i = tid; i < 64 * 16; i += 256) {
    int rr = i >> 4, kb = i & 15;
    int grow = row0 + rr;
    uint4 v = make_uint4(0, 0, 0, 0);
    if (grow < NROW) {
      float4 lo = *(const float4*)&x[(size_t)grow * D + kb * 8];
      float4 hi = *(const float4*)&x[(size_t)grow * D + kb * 8 + 4];
      v.x = ((unsigned)f2bf(lo.y) << 16) | f2bf(lo.x);
      v.y = ((unsigned)f2bf(lo.w) << 16) | f2bf(lo.z);
      v.z = ((unsigned)f2bf(hi.y) << 16) | f2bf(hi.x);
      v.w = ((unsigned)f2bf(hi.w) << 16) | f2bf(hi.z);
    }
    *(uint4*)(As + rr * 256 + ((kb * 16) ^ ((rr & 7) << 4))) = v;
  }
  int wid = tid >> 6, lane = tid & 63;
  int lr = lane & 15, lg = lane >> 4;
  f32x4 acc[24];
#pragma unroll
  for (int i = 0; i < 24; i++) acc[i] = (f32x4){0.f, 0.f, 0.f, 0.f};
  for (int kk = 0; kk < 4; kk++) {
    __syncthreads();
    for (int i = tid; i < 384 * 4; i += 256) {
      int c = i >> 2, ko = (i & 3) * 8;
      *(uint4*)(Bs + c * 80 + ko * 2) =
          *(const uint4*)&WqkvT[(size_t)c * 128 + kk * 32 + ko];
    }
    __syncthreads();
    int ar = wid * 16 + lr;
    bf16x8 a = *(bf16x8*)(As + ar * 256 + ((kk * 64 + lg * 16) ^ ((ar & 7) << 4)));
#pragma unroll
    for (int nt = 0; nt < 24; nt++) {
      bf16x8 b = *(bf16x8*)(Bs + (nt * 16 + lr) * 80 + lg * 16);
      acc[nt] = __builtin_amdgcn_mfma_f32_16x16x32_bf16(a, b, acc[nt], 0, 0, 0);
    }
  }
  // Q: f16, prescaled by 1/sqrt(dk)
#pragma unroll
  for (int nt = 0; nt < 8; nt++) {
    int c = nt * 16 + lr;
    float bb = bq[c];
#pragma unroll
    for (int j = 0; j < 4; j++) {
      int orow = row0 + wid * 16 + lg * 4 + j;
      if (orow < NROW)
        Qh[(size_t)orow * D + c] = (_Float16)((acc[nt][j] + bb) * 0.25f);
    }
  }
  // K/V interleaved: KV[row][c>>1] = (k_c|k_c+1, v_c|v_c+1), written by even lr
#pragma unroll
  for (int nt = 0; nt < 8; nt++) {
    int c = nt * 16 + lr;
    float bbk = bk[c], bbv = bv[c];
#pragma unroll
    for (int j = 0; j < 4; j++) {
      int orow = row0 + wid * 16 + lg * 4 + j;
      unsigned ku =
          (unsigned)__builtin_bit_cast(unsigned short, (_Float16)(acc[nt + 8][j] + bbk));
      unsigned vu =
          (unsigned)__builtin_bit_cast(unsigned short, (_Float16)(acc[nt + 16][j] + bbv));
      unsigned kn = __shfl_xor(ku, 1, 64);
      unsigned vn = __shfl_xor(vu, 1, 64);
      if ((lr & 1) == 0 && orow < NROW)
        KV[(size_t)orow * 64 + (c >> 1)] = make_uint2((kn << 16) | ku, (vn << 16) | vu);
    }
  }
}

// ---------------- fused attention: half-wave edge pairing, x2 unrolled ----------------
DEV_INLINE float waveReduceSum(float v) {
#pragma unroll
  for (int m = 1; m < 64; m <<= 1) v += __shfl_xor(v, m, 64);
  return v;
}

template <int TS, bool TAIL>
DEV_INLINE void procPair(uint4 kv, const h2* q01, const h2* q23, float* dr, float* ds,
                         float (*ar)[4], float (*as)[4], float valid) {
  h2 k01 = __builtin_bit_cast(h2, kv.x);
  h2 v01 = __builtin_bit_cast(h2, kv.y);
  h2 k23 = __builtin_bit_cast(h2, kv.z);
  h2 v23 = __builtin_bit_cast(h2, kv.w);
  float v0 = (float)v01[0], v1 = (float)v01[1];
  float v2 = (float)v23[0], v3 = (float)v23[1];
#pragma unroll
  for (int tt = TS; tt < 3; tt++) {
    float a = __builtin_amdgcn_fdot2(q23[tt], k23, 0.f, false);
    a = __builtin_amdgcn_fdot2(q01[tt], k01, a, false);
    a += __shfl_xor(a, 1, 64);
    a += __shfl_xor(a, 2, 64);  // head dot complete within 4-lane group
    float e = __expf(a), f = __expf(-a);
    if (TAIL) { e *= valid; f *= valid; }
    dr[tt] += e; ds[tt] += f;
    ar[tt][0] += e * v0; ar[tt][1] += e * v1;
    ar[tt][2] += e * v2; ar[tt][3] += e * v3;
    as[tt][0] += f * v0; as[tt][1] += f * v1;
    as[tt][2] += f * v2; as[tt][3] += f * v3;
  }
}

__global__ __launch_bounds__(256) void k_attn(
    const _Float16* __restrict__ Qh, const uint2* __restrict__ KV,
    const float* __restrict__ x, const int* __restrict__ offsets,
    const int* __restrict__ elist, const float* __restrict__ lng,
    const float* __restrict__ lnb, bf16* __restrict__ hB, bf16* __restrict__ rb) {
  int n = blockIdx.x * 4 + (threadIdx.x >> 6);
  int l = threadIdx.x & 63;
  int sl = l & 31, half = l >> 5;
  h2 q01[3], q23[3];
#pragma unroll
  for (int tt = 0; tt < 3; tt++) {
    uint2 qu = *(const uint2*)&Qh[((size_t)tt * NN + n) * D + 4 * sl];
    q01[tt] = __builtin_bit_cast(h2, qu.x);
    q23[tt] = __builtin_bit_cast(h2, qu.y);
  }
  float dr[3] = {0.f, 0.f, 0.f}, ds[3] = {0.f, 0.f, 0.f};
  float ar[3][4] = {{0.f}}, as[3][4] = {{0.f}};
#define TSEC(TT)                                                              \
  {                                                                           \
    const int* off = offsets + TT * (NN + 1);                                 \
    int b = off[n], e = off[n + 1];                                           \
    const int* el = elist + TT * NE;                                          \
    const uint2* KVt = KV + (size_t)TT * NN * 64;                             \
    int i = b;                                                                \
    for (; i + 4 <= e; i += 4) {                                              \
      int s0 = el[i + half];                                                  \
      int s1 = el[i + 2 + half];                                              \
      uint4 kv0 = *(const uint4*)&KVt[(size_t)s0 * 64 + 2 * sl];              \
      uint4 kv1 = *(const uint4*)&KVt[(size_t)s1 * 64 + 2 * sl];              \
      procPair<TT, false>(kv0, q01, q23, dr, ds, ar, as, 1.f);                \
      procPair<TT, false>(kv1, q01, q23, dr, ds, ar, as, 1.f);                \
    }                                                                         \
    for (; i + 2 <= e; i += 2) {                                              \
      int s = el[i + half];                                                   \
      uint4 kv = *(const uint4*)&KVt[(size_t)s * 64 + 2 * sl];                \
      procPair<TT, false>(kv, q01, q23, dr, ds, ar, as, 1.f);                 \
    }                                                                         \
    if (i < e) {                                                              \
      int s = el[i];                                                          \
      uint4 kv = *(const uint4*)&KVt[(size_t)s * 64 + 2 * sl];                \
      procPair<TT, true>(kv, q01, q23, dr, ds, ar, as, half ? 0.f : 1.f);     \
    }                                                                         \
  }
  TSEC(0)
  TSEC(1)
  TSEC(2)
#undef TSEC
#pragma unroll
  for (int tt = 0; tt < 3; tt++) {
    dr[tt] += __shfl_xor(dr[tt], 32, 64);
    ds[tt] += __shfl_xor(ds[tt], 32, 64);
#pragma unroll
    for (int d4 = 0; d4 < 4; d4++) {
      ar[tt][d4] += __shfl_xor(ar[tt][d4], 32, 64);
      as[tt][d4] += __shfl_xor(as[tt][d4], 32, 64);
    }
  }
  float4 g4 = *(const float4*)&lng[4 * sl];
  float4 b4 = *(const float4*)&lnb[4 * sl];
#pragma unroll
  for (int tt = 0; tt < 3; tt++) {
    float4 xr = *(const float4*)&x[((size_t)tt * NN + n) * D + 4 * sl];
    float ir = 1.f / (dr[tt] + 1e-16f), is = 1.f / (ds[tt] + 1e-16f);
    float hc[4], hs[4];
    hc[0] = ar[tt][0] * ir + xr.x;
    hc[1] = ar[tt][1] * ir + xr.y;
    hc[2] = ar[tt][2] * ir + xr.z;
    hc[3] = ar[tt][3] * ir + xr.w;
#pragma unroll
    for (int j = 0; j < 4; j++) hs[j] = as[tt][j] * is;
    float mu = waveReduceSum(hc[0] + hc[1] + hc[2] + hc[3]) * (1.f / 256.f);
    float dx[4], ss = 0.f;
#pragma unroll
    for (int j = 0; j < 4; j++) { dx[j] = hc[j] - mu; ss += dx[j] * dx[j]; }
    float var = waveReduceSum(ss) * (1.f / 256.f);
    float rstd = rsqrtf(var + 1e-5f);
    float rc[4];
    rc[0] = dx[0] * rstd * g4.x + b4.x;
    rc[1] = dx[1] * rstd * g4.y + b4.y;
    rc[2] = dx[2] * rstd * g4.z + b4.z;
    rc[3] = dx[3] * rstd * g4.w + b4.w;
    float mu2 = waveReduceSum(hs[0] + hs[1] + hs[2] + hs[3]) * (1.f / 256.f);
    float ex[4], ss2 = 0.f;
#pragma unroll
    for (int j = 0; j < 4; j++) { ex[j] = hs[j] - mu2; ss2 += ex[j] * ex[j]; }
    float var2 = waveReduceSum(ss2) * (1.f / 256.f);
    float rstd2 = rsqrtf(var2 + 1e-5f);
    float rs[4];
    rs[0] = ex[0] * rstd2 * g4.x + b4.x;
    rs[1] = ex[1] * rstd2 * g4.y + b4.y;
    rs[2] = ex[2] * rstd2 * g4.z + b4.z;
    rs[3] = ex[3] * rstd2 * g4.w + b4.w;
    if (half == 0) {
      size_t base = (size_t)tt * 2 * NN;
      size_t iC = (base + n) * D + 4 * sl;
      size_t iS = (base + NN + n) * D + 4 * sl;
      *(uint2*)&hB[iC] = make_uint2(((unsigned)f2bf(hc[1]) << 16) | f2bf(hc[0]),
                                    ((unsigned)f2bf(hc[3]) << 16) | f2bf(hc[2]));
      *(uint2*)&hB[iS] = make_uint2(((unsigned)f2bf(hs[1]) << 16) | f2bf(hs[0]),
                                    ((unsigned)f2bf(hs[3]) << 16) | f2bf(hs[2]));
      *(uint2*)&rb[iC] = make_uint2(((unsigned)f2bf(rc[1]) << 16) | f2bf(rc[0]),
                                    ((unsigned)f2bf(rc[3]) << 16) | f2bf(rc[2]));
      *(uint2*)&rb[iS] = make_uint2(((unsigned)f2bf(rs[1]) << 16) | f2bf(rs[0]),
                                    ((unsigned)f2bf(rs[3]) << 16) | f2bf(rs[2]));
    }
  }
}

// ---------------- fused FFN v9: fast gelu, grid 512, in-register combine ----------------
__global__ __launch_bounds__(512) void k_ffn_fused(
    const bf16* __restrict__ rb, const bf16* __restrict__ W1L,
    const bf16* __restrict__ W2L, const float* __restrict__ b1,
    const float* __restrict__ b2, const bf16* __restrict__ h,
    float* __restrict__ out) {
  __shared__ char As[32 * 256];  // rb tile, XOR-swizzled
  __shared__ char Gs[32 * 528];  // gelu tile bf16
  int tid = threadIdx.x;
  int wid = tid >> 6, lane = tid & 63;
  int lr = lane & 15, lg = lane >> 4;
  int wr = (wid & 1) * 16;
  int wc1 = (wid >> 1) * 64;
  int wc2 = (wid >> 1) * 32;
  int ar = wr + lr;
  bf16x8 w1f[4][4];  // [kk][nt]
#pragma unroll
  for (int kk = 0; kk < 4; kk++)
#pragma unroll
    for (int nt = 0; nt < 4; nt++)
      w1f[kk][nt] =
          *(const bf16x8*)&W1L[((size_t)kk * 256 + wc1 + nt * 16 + lr) * 32 + lg * 8];
  bf16x8 w2f[8][2];
#pragma unroll
  for (int kk = 0; kk < 8; kk++)
#pragma unroll
    for (int nt = 0; nt < 2; nt++)
      w2f[kk][nt] =
          *(const bf16x8*)&W2L[((size_t)kk * 128 + wc2 + nt * 16 + lr) * 32 + lg * 8];
  float bb1[4], bb2[2];
#pragma unroll
  for (int nt = 0; nt < 4; nt++) bb1[nt] = b1[wc1 + nt * 16 + lr];
#pragma unroll
  for (int nt = 0; nt < 2; nt++) bb2[nt] = b2[wc2 + nt * 16 + lr];
  int srr = tid >> 4, skb = tid & 15;  // As staging slot (1 uint4/thread)
  int tile = blockIdx.x;
  uint4 pref;
  {
    int t2 = tile / 1250, nb = tile - t2 * 1250;
    size_t grow = (size_t)t2 * 2 * NN + (size_t)(srr & 1) * NN + nb * 16 + (srr >> 1);
    pref = *(const uint4*)&rb[grow * D + skb * 8];
  }
  for (; tile < NTILE; tile += gridDim.x) {
    int t2 = tile / 1250, nb = tile - t2 * 1250;
    int n0 = nb * 16;
    size_t base = (size_t)t2 * 2 * NN;
    *(uint4*)(As + srr * 256 + ((skb * 16) ^ ((srr & 7) << 4))) = pref;
    float hpref[2][4];
#pragma unroll
    for (int nt = 0; nt < 2; nt++) {
      int c = wc2 + nt * 16 + lr;
#pragma unroll
      for (int j = 0; j < 4; j++) {
        int rr2 = wr + lg * 4 + j;
        hpref[nt][j] = bf2f(*(const unsigned short*)&h[
            (base + (size_t)(rr2 & 1) * NN + n0 + (rr2 >> 1)) * D + c]);
      }
    }
    int ntile = tile + gridDim.x;
    if (ntile < NTILE) {
      int t2n = ntile / 1250, nbn = ntile - t2n * 1250;
      size_t grow =
          (size_t)t2n * 2 * NN + (size_t)(srr & 1) * NN + nbn * 16 + (srr >> 1);
      pref = *(const uint4*)&rb[grow * D + skb * 8];
    }
    __syncthreads();  // As ready; also orders prev GEMM2 Gs-reads before Gs writes
    f32x4 acc1[4];
#pragma unroll
    for (int i = 0; i < 4; i++) acc1[i] = (f32x4){0.f, 0.f, 0.f, 0.f};
#pragma unroll
    for (int kk = 0; kk < 4; kk++) {
      bf16x8 a = *(bf16x8*)(As + ar * 256 + ((kk * 64 + lg * 16) ^ ((ar & 7) << 4)));
#pragma unroll
      for (int nt = 0; nt < 4; nt++)
        acc1[nt] =
            __builtin_amdgcn_mfma_f32_16x16x32_bf16(a, w1f[kk][nt], acc1[nt], 0, 0, 0);
    }
#pragma unroll
    for (int nt = 0; nt < 4; nt++) {
      int c = wc1 + nt * 16 + lr;
#pragma unroll
      for (int j = 0; j < 4; j++) {
        int r = wr + lg * 4 + j;
        float y = gelu_fast(acc1[nt][j] + bb1[nt]);
        unsigned us = f2bf(y);
        unsigned nbv = __shfl_xor(us, 1, 64);
        if ((lr & 1) == 0) *(unsigned*)(Gs + r * 528 + c * 2) = (nbv << 16) | us;
      }
    }
    __syncthreads();  // Gs ready
    f32x4 acc2[2];
#pragma unroll
    for (int i = 0; i < 2; i++) acc2[i] = (f32x4){0.f, 0.f, 0.f, 0.f};
#pragma unroll
    for (int kk = 0; kk < 8; kk++) {
      bf16x8 a = *(bf16x8*)(Gs + ar * 528 + kk * 64 + lg * 16);
#pragma unroll
      for (int nt = 0; nt < 2; nt++)
        acc2[nt] =
            __builtin_amdgcn_mfma_f32_16x16x32_bf16(a, w2f[kk][nt], acc2[nt], 0, 0, 0);
    }
    // epilogue fully in-register: j pairs (2m,2m+1) = (causal,spurious) of one node
#pragma unroll
    for (int nt = 0; nt < 2; nt++) {
      int c = wc2 + nt * 16 + lr;
      float z[4];
#pragma unroll
      for (int j = 0; j < 4; j++) z[j] = acc2[nt][j] + bb2[nt] + hpref[nt][j];
#pragma unroll
      for (int m = 0; m < 2; m++) {
        int node = n0 + ((wr + lg * 4) >> 1) + m;
        size_t oidx = ((size_t)t2 * NN + node) * D + c;
        out[OUTSZ + oidx] = z[2 * m];          // cs
        out[2 * OUTSZ + oidx] = z[2 * m + 1];  // ss
        out[oidx] = z[2 * m] + z[2 * m + 1];   // xs
      }
    }
  }
}

}  // namespace

extern "C" void kernel_launch(void* const* d_in, const int* in_sizes, int n_in,
                              void* d_out, int out_size, void* d_ws, size_t ws_size,
                              hipStream_t stream) {
  const float* x = (const float*)d_in[0];
  const void* ei = d_in[1];  // int32 or int64 — probed on device
  const float* Wq = (const float*)d_in[2];
  const float* bq = (const float*)d_in[3];
  const float* Wk = (const float*)d_in[4];
  const float* bk = (const float*)d_in[5];
  const float* Wv = (const float*)d_in[6];
  const float* bv = (const float*)d_in[7];
  const float* lng = (const float*)d_in[8];
  const float* lnb = (const float*)d_in[9];
  const float* W1 = (const float*)d_in[10];
  const float* b1 = (const float*)d_in[11];
  const float* W2 = (const float*)d_in[12];
  const float* b2 = (const float*)d_in[13];
  float* out = (float*)d_out;

  char* ws = (char*)d_ws;
  size_t off = 0;
  auto alloc = [&](size_t bytes) -> void* {
    void* p = ws + off;
    off += (bytes + 255) & ~(size_t)255;
    return p;
  };
  bf16* WqkvT = (bf16*)alloc((size_t)384 * 128 * 2);
  bf16* W1L = (bf16*)alloc((size_t)128 * 256 * 2);
  bf16* W2L = (bf16*)alloc((size_t)256 * 128 * 2);
  _Float16* Qh = (_Float16*)alloc((size_t)NROW * D * 2);
  uint2* KV = (uint2*)alloc((size_t)NROW * 64 * 8);
  bf16* hB = (bf16*)alloc((size_t)T * 2 * NN * D * 2);  // [t][side][node] bf16
  bf16* rb = (bf16*)alloc((size_t)T * 2 * NN * D * 2);
  int* counts = (int*)alloc((size_t)T * NN * 4);
  int* offsets = (int*)alloc((size_t)T * (NN + 1) * 4);
  int* cursor = (int*)alloc((size_t)T * NN * 4);
  int* elist = (int*)alloc((size_t)T * NE * 4);
  int* dflag = (int*)alloc(256);

  hipMemsetAsync(counts, 0, (size_t)T * NN * 4, stream);
  hipMemsetAsync(dflag, 0, 8, stream);
  k_detect<<<1, 256, 0, stream>>>((const unsigned int*)ei, dflag);
  int eb = (T * NE + 255) / 256;
  k_count_precast<<<eb, 256, 0, stream>>>(ei, dflag, counts, Wq, Wk, Wv, W1, W2,
                                          WqkvT, W1L, W2L);
  k_scan<<<T, 256, 0, stream>>>(counts, offsets, cursor);
  k_scatter<<<eb, 256, 0, stream>>>(ei, dflag, cursor, elist);
  k_qkv_mfma<<<(NROW + 63) / 64, 256, 0, stream>>>(x, WqkvT, bq, bk, bv, Qh, KV);
  k_attn<<<NN / 4, 256, 0, stream>>>(Qh, KV, x, offsets, elist, lng, lnb, hB, rb);
  k_ffn_fused<<<512, 512, 0, stream>>>(rb, W1L, W2L, b1, b2, hB, out);
}